// Round 7
// baseline (293.568 us; speedup 1.0000x reference)
//
#include <hip/hip_runtime.h>
#include <stdint.h>

#define D_DIM   4096
#define THREADS 256
#define NBINS   4096          // 12-bit first digit
#define RPB     4             // rows per block, software-pipelined

// Barrier that orders LDS only (lgkmcnt) — leaves global prefetch loads
// (vmcnt) in flight, unlike __syncthreads() which drains vmcnt(0).
__device__ __forceinline__ void bar_lds() {
    asm volatile("s_waitcnt lgkmcnt(0)" ::: "memory");
    __builtin_amdgcn_s_barrier();
    asm volatile("" ::: "memory");
}

__global__ __launch_bounds__(THREADS, 8)
void kwta_kernel(const float* __restrict__ x, const int* __restrict__ kptr,
                 float* __restrict__ out) {
    __shared__ uint32_t hist[NBINS];      // 16 KB; reused as survivor buffer
    __shared__ uint32_t wtot[4];
    __shared__ int pub_bin, pub_kp, ns;

    const int t    = threadIdx.x;
    const int wid  = t >> 6;
    const int lane = t & 63;
    const uint32_t uk = (uint32_t)kptr[0];
    const size_t base0 = (size_t)blockIdx.x * RPB * D_DIM;

    // Prologue: prefetch row 0 raw into registers.
    float4 nv[4];
    {
        const float4* __restrict__ xr = reinterpret_cast<const float4*>(x + base0);
        #pragma unroll
        for (int j = 0; j < 4; ++j) nv[j] = xr[t + j * THREADS];
    }

    #pragma unroll 1
    for (int g = 0; g < RPB; ++g) {
        const size_t base = base0 + (size_t)g * D_DIM;

        // Consume prefetch (vmcnt wait lands here), map to order-preserving uint.
        uint32_t u[16];
        #pragma unroll
        for (int j = 0; j < 4; ++j) {
            uint32_t b[4] = { __float_as_uint(nv[j].x), __float_as_uint(nv[j].y),
                              __float_as_uint(nv[j].z), __float_as_uint(nv[j].w) };
            #pragma unroll
            for (int e = 0; e < 4; ++e) {
                uint32_t f = b[e];
                u[j * 4 + e] = ((int32_t)f < 0) ? ~f : (f | 0x80000000u);
            }
        }
        // Issue next row's loads NOW; they fly across all lgkm-only barriers.
        if (g + 1 < RPB) {
            const float4* __restrict__ xr =
                reinterpret_cast<const float4*>(x + base + D_DIM);
            #pragma unroll
            for (int j = 0; j < 4; ++j) nv[j] = xr[t + j * THREADS];
        }

        // Zero histogram + survivor counter.
        #pragma unroll
        for (int j = 0; j < 4; ++j)
            reinterpret_cast<uint4*>(hist)[t + j * THREADS] = make_uint4(0, 0, 0, 0);
        if (t == 0) ns = 0;
        bar_lds();                                     // B1

        // 12-bit histogram of top bits.
        #pragma unroll
        for (int e = 0; e < 16; ++e)
            atomicAdd(&hist[u[e] >> 20], 1u);
        bar_lds();                                     // B2

        // Cooperative suffix scan; thread owns bins [16t,16t+16) as 4 uint4
        // groups, keeps only group sums (re-reads winning uint4 when drilling).
        uint32_t g4[4]; uint32_t T = 0;
        #pragma unroll
        for (int j = 0; j < 4; ++j) {
            uint4 hv = reinterpret_cast<const uint4*>(hist)[4 * t + j];
            g4[j] = hv.x + hv.y + hv.z + hv.w;
            T += g4[j];
        }
        uint32_t W = T;                                // wave incl. suffix scan
        #pragma unroll
        for (int m = 1; m <= 32; m <<= 1) {
            uint32_t o = (uint32_t)__shfl_down((int)W, m, 64);
            if (lane + m < 64) W += o;
        }
        if (lane == 0) wtot[wid] = W;
        bar_lds();                                     // B3
        uint32_t above = W - T;
        #pragma unroll
        for (int w = 0; w < 4; ++w)
            if (w > wid) above += wtot[w];
        if (above < uk && uk <= above + T) {           // exactly one thread
            uint32_t cum = above;
            int jg = 0; bool fj = false;
            #pragma unroll
            for (int j = 3; j >= 0; --j) {             // static idx, no scratch
                if (!fj) {
                    if (cum + g4[j] >= uk) { jg = j; fj = true; }
                    else cum += g4[j];
                }
            }
            uint4 hv = reinterpret_cast<const uint4*>(hist)[4 * t + jg];
            uint32_t c4[4] = { hv.x, hv.y, hv.z, hv.w };
            int be = 0; bool fe = false;
            #pragma unroll
            for (int e = 3; e >= 0; --e) {
                if (!fe) {
                    if (cum + c4[e] >= uk) { be = e; fe = true; }
                    else cum += c4[e];
                }
            }
            pub_bin = 16 * t + 4 * jg + be;
            pub_kp  = (int)(uk - cum);                 // 1-based rank within bin
        }
        bar_lds();                                     // B4
        const uint32_t bin = (uint32_t)pub_bin;
        const int kp = pub_kp;

        // Extraction: ballot pass 1 (count) -> one atomic/wave -> pass 2 (write).
        const unsigned long long lt = (1ull << lane) - 1ull;
        uint32_t mm = 0; int cnt = 0;
        #pragma unroll
        for (int e = 0; e < 16; ++e) {
            const bool m = (u[e] >> 20) == bin;
            unsigned long long mk = __ballot(m);
            cnt += (int)__popcll(mk);
            if (m) mm |= (1u << e);
        }
        int wbase = 0;
        if (lane == 0) wbase = atomicAdd(&ns, cnt);
        wbase = __builtin_amdgcn_readfirstlane(wbase);
        int run = wbase;
        #pragma unroll
        for (int e = 0; e < 16; ++e) {
            const bool m = (mm >> e) & 1u;
            unsigned long long mk = __ballot(m);
            if (m) hist[run + (int)__popcll(mk & lt)] = u[e];
            run += (int)__popcll(mk);
        }
        bar_lds();                                     // B5
        const int N = ns;

        // Bisect low 20 bits among survivors; redundant per wave, no barriers.
        uint32_t lo = 0, hi = 0xFFFFFu;
        if (N <= 256) {
            uint32_t v[4];
            #pragma unroll
            for (int c = 0; c < 4; ++c) {
                int idx = 64 * c + lane;
                v[c] = (idx < N) ? (hist[idx] & 0xFFFFFu) : 0u;
            }
            #pragma unroll 1
            while (lo < hi) {
                uint32_t mid = lo + ((hi - lo + 1u) >> 1);
                int c = 0;
                #pragma unroll
                for (int j = 0; j < 4; ++j)
                    c += (int)__popcll(__ballot(v[j] >= mid));
                if (c >= kp) lo = mid; else hi = mid - 1u;
            }
        } else {
            #pragma unroll 1
            while (lo < hi) {
                uint32_t mid = lo + ((hi - lo + 1u) >> 1);
                int c = 0;
                for (int cb = 0; cb < N; cb += 64) {
                    uint32_t vv = 0;
                    if (cb + lane < N) vv = hist[cb + lane] & 0xFFFFFu;
                    c += (int)__popcll(__ballot(vv >= mid));
                }
                if (c >= kp) lo = mid; else hi = mid - 1u;
            }
        }
        const uint32_t thr = (bin << 20) | lo;         // exact k-th largest pattern

        // Write output from registers.
        float4* __restrict__ orow = reinterpret_cast<float4*>(out + base);
        #pragma unroll
        for (int j = 0; j < 4; ++j) {
            float4 o;
            float* po = &o.x;
            #pragma unroll
            for (int e = 0; e < 4; ++e) {
                uint32_t uu = u[j * 4 + e];
                uint32_t f  = (uu & 0x80000000u) ? (uu ^ 0x80000000u) : ~uu;
                po[e] = (uu >= thr) ? __uint_as_float(f) : 0.0f;
            }
            orow[t + j * THREADS] = o;
        }
        if (g + 1 < RPB) bar_lds();                    // B6: survivor reads vs next zero
    }
}

extern "C" void kernel_launch(void* const* d_in, const int* in_sizes, int n_in,
                              void* d_out, int out_size, void* d_ws, size_t ws_size,
                              hipStream_t stream) {
    const float* x    = (const float*)d_in[0];
    const int*   kptr = (const int*)d_in[1];
    float*       out  = (float*)d_out;
    const int rows   = out_size / D_DIM;        // 8192
    const int blocks = rows / RPB;              // 2048
    kwta_kernel<<<blocks, THREADS, 0, stream>>>(x, kptr, out);
}

// Round 8
// 251.640 us; speedup vs baseline: 1.1666x; 1.1666x over previous
//
#include <hip/hip_runtime.h>
#include <stdint.h>

#define D_DIM    4096
#define THREADS  256
#define NBINS    2048        // 11-bit first digit
#define RPB      8           // rows per block (persistent); grid = 8192/8 = 1024
#define SURV_CAP 1024

// Barrier ordering LDS only — leaves global_load_lds prefetch (vmcnt) in flight.
__device__ __forceinline__ void bar_lds() {
    asm volatile("s_waitcnt lgkmcnt(0)" ::: "memory");
    __builtin_amdgcn_s_barrier();
    asm volatile("" ::: "memory");
}
// Full barrier — drains vmcnt too (used once per row, when prefetch must have landed).
__device__ __forceinline__ void bar_full() {
    asm volatile("s_waitcnt vmcnt(0) lgkmcnt(0)" ::: "memory");
    __builtin_amdgcn_s_barrier();
    asm volatile("" ::: "memory");
}

typedef const __attribute__((address_space(1))) uint32_t* gas_p;
typedef __attribute__((address_space(3))) uint32_t*       las_p;

// Async global->LDS: wave-uniform LDS base + lane*16 (m104 constraint), linear layout.
__device__ __forceinline__ void prefetch_row(const float* rowp, uint32_t* rowbuf,
                                             int wid, int lane) {
    #pragma unroll
    for (int j = 0; j < 4; ++j) {
        const float* g = rowp + (wid * 1024 + j * 256 + lane * 4);
        uint32_t*    l = rowbuf + (wid * 1024 + j * 256);     // wave-uniform base
        __builtin_amdgcn_global_load_lds((gas_p)(const void*)g, (las_p)(void*)l,
                                         16, 0, 0);
    }
}

__global__ __launch_bounds__(THREADS, 4)
void kwta_kernel(const float* __restrict__ x, const int* __restrict__ kptr,
                 float* __restrict__ out) {
    __shared__ __align__(16) uint32_t hist2[2][NBINS];   // 16 KB ping-pong
    __shared__ __align__(16) uint32_t rowbuf[D_DIM];     // 16 KB prefetch target
    __shared__ __align__(16) uint32_t surv[SURV_CAP];    // 4 KB survivors
    __shared__ int pub_bin, pub_kp, ns, fcnt;

    const int t    = threadIdx.x;
    const int wid  = t >> 6;
    const int lane = t & 63;
    const uint32_t uk = (uint32_t)kptr[0];
    const size_t base0 = (size_t)blockIdx.x * RPB * D_DIM;

    // Prologue: zero both hists; prefetch row 0.
    #pragma unroll
    for (int j = 0; j < 4; ++j)
        reinterpret_cast<uint4*>(&hist2[0][0])[t + j * THREADS] = make_uint4(0, 0, 0, 0);
    if (t == 0) ns = 0;
    prefetch_row(x + base0, rowbuf, wid, lane);

    #pragma unroll 1
    for (int g = 0; g < RPB; ++g) {
        bar_full();                                      // B1: prefetch g landed

        // Consume rowbuf -> u (order-preserving uint map).
        uint32_t u[16];
        #pragma unroll
        for (int j = 0; j < 4; ++j) {
            uint4 rv = reinterpret_cast<const uint4*>(rowbuf)[t + j * THREADS];
            uint32_t b[4] = { rv.x, rv.y, rv.z, rv.w };
            #pragma unroll
            for (int e = 0; e < 4; ++e) {
                uint32_t f = b[e];
                u[j * 4 + e] = ((int32_t)f < 0) ? ~f : (f | 0x80000000u);
            }
        }
        bar_lds();                                       // B2: rowbuf free

        // Prefetch next row (overwrites rowbuf; flies across lgkm barriers);
        // zero the other hist (ping-pong); reset ns; histogram atomics.
        if (g + 1 < RPB)
            prefetch_row(x + base0 + (size_t)(g + 1) * D_DIM, rowbuf, wid, lane);
        uint32_t* __restrict__ h  = hist2[g & 1];
        uint32_t* __restrict__ hz = hist2[(g + 1) & 1];
        reinterpret_cast<uint4*>(hz)[t]           = make_uint4(0, 0, 0, 0);
        reinterpret_cast<uint4*>(hz)[t + THREADS] = make_uint4(0, 0, 0, 0);
        if (t == 0) ns = 0;
        #pragma unroll
        for (int e = 0; e < 16; ++e)
            atomicAdd(&h[u[e] >> 21], 1u);
        bar_lds();                                       // B3: hist ready

        // Single-wave scan + drill (lane owns 32 bins as 8 uint4 groups).
        if (wid == 0) {
            const uint4* __restrict__ h4 = reinterpret_cast<const uint4*>(h);
            uint32_t gs[8]; uint32_t T = 0;
            #pragma unroll
            for (int j = 0; j < 8; ++j) {
                uint4 hv = h4[lane * 8 + j];
                gs[j] = hv.x + hv.y + hv.z + hv.w;
                T += gs[j];
            }
            uint32_t W = T;                              // wave incl. suffix scan
            #pragma unroll
            for (int m = 1; m <= 32; m <<= 1) {
                uint32_t o = (uint32_t)__shfl_down((int)W, m, 64);
                if (lane + m < 64) W += o;
            }
            const uint32_t above = W - T;
            if (above < uk && uk <= above + T) {         // exactly one lane
                uint32_t cum = above;
                int jg = 0; bool fj = false;
                #pragma unroll
                for (int j = 7; j >= 0; --j)             // static idx, no scratch
                    if (!fj) {
                        if (cum + gs[j] >= uk) { jg = j; fj = true; }
                        else cum += gs[j];
                    }
                uint4 hv = h4[lane * 8 + jg];
                uint32_t c4[4] = { hv.x, hv.y, hv.z, hv.w };
                int be = 0; bool fe = false;
                #pragma unroll
                for (int e2 = 3; e2 >= 0; --e2)
                    if (!fe) {
                        if (cum + c4[e2] >= uk) { be = e2; fe = true; }
                        else cum += c4[e2];
                    }
                pub_bin = lane * 32 + jg * 4 + be;
                pub_kp  = (int)(uk - cum);               // 1-based rank in bin
            }
        }
        bar_lds();                                       // B4: bin published
        const uint32_t bin = (uint32_t)pub_bin;
        const int      kp  = pub_kp;

        // Extraction: ballot pass 1 (count) -> one atomic/wave -> pass 2 (write).
        const unsigned long long lt = (1ull << lane) - 1ull;
        uint32_t mm = 0; int cnt = 0;
        #pragma unroll
        for (int e = 0; e < 16; ++e) {
            const bool m = (u[e] >> 21) == bin;
            unsigned long long mk = __ballot(m);
            cnt += (int)__popcll(mk);
            if (m) mm |= (1u << e);
        }
        int wbase = 0;
        if (lane == 0) wbase = atomicAdd(&ns, cnt);
        wbase = __builtin_amdgcn_readfirstlane(wbase);
        int run = wbase;
        #pragma unroll
        for (int e = 0; e < 16; ++e) {
            const bool m = (mm >> e) & 1u;
            unsigned long long mk = __ballot(m);
            if (m) {
                int pos = run + (int)__popcll(mk & lt);
                if (pos < SURV_CAP) surv[pos] = u[e];
            }
            run += (int)__popcll(mk);
        }
        bar_lds();                                       // B5: survivors ready
        const int N = ns;

        // Bisect low 21 bits among survivors for kp-th largest.
        uint32_t lo = 0, hi = 0x1FFFFFu;
        if (N <= 256) {                                  // register path (typical)
            uint32_t v[4];
            #pragma unroll
            for (int c = 0; c < 4; ++c) {
                int idx = 64 * c + lane;
                v[c] = (idx < N) ? (surv[idx] & 0x1FFFFFu) : 0u;
            }
            #pragma unroll 1
            while (lo < hi) {
                uint32_t mid = lo + ((hi - lo + 1u) >> 1);
                int c = 0;
                #pragma unroll
                for (int j = 0; j < 4; ++j)
                    c += (int)__popcll(__ballot(v[j] >= mid));
                if (c >= kp) lo = mid; else hi = mid - 1u;
            }
        } else if (N <= SURV_CAP) {                      // chunked LDS path (rare)
            #pragma unroll 1
            while (lo < hi) {
                uint32_t mid = lo + ((hi - lo + 1u) >> 1);
                int c = 0;
                for (int cb = 0; cb < N; cb += 64) {
                    uint32_t vv = 0;
                    if (cb + lane < N) vv = surv[cb + lane] & 0x1FFFFFu;
                    c += (int)__popcll(__ballot(vv >= mid));
                }
                if (c >= kp) lo = mid; else hi = mid - 1u;
            }
        } else {                                         // overflow fallback (never
            #pragma unroll 1                             // on this data): cross-wave
            while (lo < hi) {                            // count from registers
                uint32_t mid = lo + ((hi - lo + 1u) >> 1);
                if (t == 0) fcnt = 0;
                bar_lds();
                int c = 0;
                #pragma unroll
                for (int e = 0; e < 16; ++e)
                    c += (int)__popcll(__ballot(((u[e] >> 21) == bin) &&
                                                ((u[e] & 0x1FFFFFu) >= mid)));
                if (lane == 0) atomicAdd(&fcnt, c);
                bar_lds();
                int tot = fcnt;
                bar_lds();
                if (tot >= kp) lo = mid; else hi = mid - 1u;
            }
        }
        const uint32_t thr = (bin << 21) | lo;           // exact k-th largest pattern

        // Write output from registers (fire-and-forget stores).
        float4* __restrict__ orow =
            reinterpret_cast<float4*>(out + base0 + (size_t)g * D_DIM);
        #pragma unroll
        for (int j = 0; j < 4; ++j) {
            float4 o;
            float* po = &o.x;
            #pragma unroll
            for (int e = 0; e < 4; ++e) {
                uint32_t uu = u[j * 4 + e];
                uint32_t f  = (uu & 0x80000000u) ? (uu ^ 0x80000000u) : ~uu;
                po[e] = (uu >= thr) ? __uint_as_float(f) : 0.0f;
            }
            orow[t + j * THREADS] = o;
        }
    }
}

extern "C" void kernel_launch(void* const* d_in, const int* in_sizes, int n_in,
                              void* d_out, int out_size, void* d_ws, size_t ws_size,
                              hipStream_t stream) {
    const float* x    = (const float*)d_in[0];
    const int*   kptr = (const int*)d_in[1];
    float*       out  = (float*)d_out;
    const int rows   = out_size / D_DIM;        // 8192
    const int blocks = rows / RPB;              // 1024 = exactly 4 per CU
    kwta_kernel<<<blocks, THREADS, 0, stream>>>(x, kptr, out);
}